// Round 1
// baseline (767.517 us; speedup 1.0000x reference)
//
#include <hip/hip_runtime.h>
#include <math.h>

#define PI_F 3.14159265358979323846f

// ---------------------------------------------------------------------------
// Problem constants: N_ORDER=256, PRED_LEN=192, SEQ_LEN=768, ENC_IN=21, B=16,
// MULTISCALE={1,2,4} -> L_s = 192<<s, MODES=32, t0 = 191.
//
// Workspace layout (float offsets):
//   w      [s][d][i]            : off 0,        len 344064   (sum L_s * 256)
//   Apow   [s][2][256*256]      : off 344064,   len 393216
//   Ktil   [s][sidx][p]         : off 737280,   len 258048   (sum L_s * 192)
//   Ktot   [tau][p]             : off 995328,   len 147456   (768*192)
//   Y      [s][ri][k][p][i]     : off 1142784,  len 9437184  (3*2*32*192*256)
//   QT region (time-shared):
//     Wt   [s][ri][k][i][o]     : off 10579968, len 12582912
//     Qd/QG[s][ri][k][d][p]     : off 10579968, len 16515072 (2*32*192*sumL)
// Total: 27,095,040 floats = 108.4 MB
// ---------------------------------------------------------------------------
#define W_OFF    0
#define AP_OFF   344064
#define KT_OFF   737280
#define KTOT_OFF 995328
#define Y_OFF    1142784
#define QT_OFF   10579968
#define WS_FLOATS 27095040

__device__ __forceinline__ int off_w_f(int s)  { return 49152  * ((1 << s) - 1); }
__device__ __forceinline__ int qoff_f(int s)   { return 2359296 * ((1 << s) - 1); }
__device__ __forceinline__ int ktoff_f(int s)  { return 36864  * ((1 << s) - 1); }

// ---------------------------------------------------------------------------
// Tiled fp32 GEMM tile: C[64x64 tile at (m0,n0)] = A @ op(B), K=256 fixed,
// lda = ldb = 256.  BT=true: C = A @ B^T (both row-major, K fastest).
// BT=false: C = A @ B (B row-major 256 x N).
// block = 256 threads, 4x4 micro-tile per thread.
// ---------------------------------------------------------------------------
template<bool BT>
__device__ __forceinline__ void gemm_tile(const float* __restrict__ A,
                                          const float* __restrict__ B,
                                          float* __restrict__ C,
                                          int M, int N, int ldc, int m0, int n0)
{
    __shared__ float As[16][68];
    __shared__ float Bs[16][68];
    const int tid = threadIdx.x;
    const int tx = tid & 15;
    const int ty = tid >> 4;
    const int r  = tid >> 2;          // 0..63
    const int kq = (tid & 3) << 2;    // 0,4,8,12

    float acc[4][4] = {{0.f,0.f,0.f,0.f},{0.f,0.f,0.f,0.f},
                       {0.f,0.f,0.f,0.f},{0.f,0.f,0.f,0.f}};

    for (int kk = 0; kk < 256; kk += 16) {
        // stage A tile (rows m0..m0+63, k cols kk..kk+15)
        float4 av = make_float4(0.f, 0.f, 0.f, 0.f);
        if (m0 + r < M)
            av = *(const float4*)(A + (size_t)(m0 + r) * 256 + kk + kq);
        As[kq + 0][r] = av.x; As[kq + 1][r] = av.y;
        As[kq + 2][r] = av.z; As[kq + 3][r] = av.w;

        if (BT) {
            float4 bv = make_float4(0.f, 0.f, 0.f, 0.f);
            if (n0 + r < N)
                bv = *(const float4*)(B + (size_t)(n0 + r) * 256 + kk + kq);
            Bs[kq + 0][r] = bv.x; Bs[kq + 1][r] = bv.y;
            Bs[kq + 2][r] = bv.z; Bs[kq + 3][r] = bv.w;
        } else {
            const int kb = tid >> 4;          // 0..15
            const int j4 = (tid & 15) << 2;   // 0..60
            float4 bv = *(const float4*)(B + (size_t)(kk + kb) * 256 + n0 + j4);
            *(float4*)(&Bs[kb][j4]) = bv;
        }
        __syncthreads();

        #pragma unroll
        for (int k = 0; k < 16; ++k) {
            float4 a4 = *(const float4*)(&As[k][ty << 2]);
            float4 b4 = *(const float4*)(&Bs[k][tx << 2]);
            acc[0][0] = fmaf(a4.x, b4.x, acc[0][0]);
            acc[0][1] = fmaf(a4.x, b4.y, acc[0][1]);
            acc[0][2] = fmaf(a4.x, b4.z, acc[0][2]);
            acc[0][3] = fmaf(a4.x, b4.w, acc[0][3]);
            acc[1][0] = fmaf(a4.y, b4.x, acc[1][0]);
            acc[1][1] = fmaf(a4.y, b4.y, acc[1][1]);
            acc[1][2] = fmaf(a4.y, b4.z, acc[1][2]);
            acc[1][3] = fmaf(a4.y, b4.w, acc[1][3]);
            acc[2][0] = fmaf(a4.z, b4.x, acc[2][0]);
            acc[2][1] = fmaf(a4.z, b4.y, acc[2][1]);
            acc[2][2] = fmaf(a4.z, b4.z, acc[2][2]);
            acc[2][3] = fmaf(a4.z, b4.w, acc[2][3]);
            acc[3][0] = fmaf(a4.w, b4.x, acc[3][0]);
            acc[3][1] = fmaf(a4.w, b4.y, acc[3][1]);
            acc[3][2] = fmaf(a4.w, b4.z, acc[3][2]);
            acc[3][3] = fmaf(a4.w, b4.w, acc[3][3]);
        }
        __syncthreads();
    }

    #pragma unroll
    for (int u = 0; u < 4; ++u) {
        int row = m0 + (ty << 2) + u;
        if (row < M) {
            float4 cv = make_float4(acc[u][0], acc[u][1], acc[u][2], acc[u][3]);
            *(float4*)(C + (size_t)row * ldc + n0 + (tx << 2)) = cv;
        }
    }
}

// ---------------------------------------------------------------------------
// w[0] = Bv per scale
// ---------------------------------------------------------------------------
__global__ void k_init(const float* B0, const float* B1, const float* B2, float* ws)
{
    int s = blockIdx.x;
    const float* Bv = (s == 0) ? B0 : (s == 1) ? B1 : B2;
    ws[W_OFF + off_w_f(s) + threadIdx.x] = Bv[threadIdx.x];
}

// ---------------------------------------------------------------------------
// doubling level n:
//   jump  : w[2^n + r] = Apow_n @ w[r], r < cnt = min(2^n, L-2^n)   (if 2^n < L)
//   square: Apow_{n+1} = Apow_n @ Apow_n                            (if 2^{n+1} < L)
// grid (4, 8, 3): x = col tile, y<4 jump row tile, y>=4 square row tile, z = scale
// ---------------------------------------------------------------------------
__global__ void k_level(int n, const float* A0, const float* A1, const float* A2,
                        float* ws)
{
    int s = blockIdx.z;
    int L = 192 << s;
    const float* Ain = (s == 0) ? A0 : (s == 1) ? A1 : A2;
    float* wbase = ws + W_OFF + off_w_f(s);
    float* bufA  = ws + AP_OFF + s * 131072;
    float* bufB  = bufA + 65536;
    const float* src = (n == 0) ? Ain : (((n - 1) & 1) ? bufB : bufA);

    int y = blockIdx.y;
    if (y < 4) {
        int p2 = 1 << n;
        if (p2 >= L) return;
        int cnt = min(p2, L - p2);
        int m0 = y * 64;
        if (m0 >= cnt) return;
        gemm_tile<true>(wbase, src, wbase + (size_t)p2 * 256,
                        cnt, 256, 256, m0, blockIdx.x * 64);
    } else {
        if ((2 << n) >= L) return;
        float* dst = (n & 1) ? bufB : bufA;
        gemm_tile<false>(src, src, dst, 256, 256, 256, (y - 4) * 64, blockIdx.x * 64);
    }
}

// ---------------------------------------------------------------------------
// Wt[s][ri][k][i][o] = W[i][o][k]   (one block per (s,ri,i), 256 threads = o)
// ---------------------------------------------------------------------------
__global__ void k_transpose(const float* Wr0, const float* Wi0,
                            const float* Wr1, const float* Wi1,
                            const float* Wr2, const float* Wi2, float* ws)
{
    int bid = blockIdx.x;
    int i  = bid & 255;
    int ri = (bid >> 8) & 1;
    int s  = bid >> 9;
    const float* W;
    if (s == 0)      W = ri ? Wi0 : Wr0;
    else if (s == 1) W = ri ? Wi1 : Wr1;
    else             W = ri ? Wi2 : Wr2;

    int o = threadIdx.x;
    int sri = s * 2 + ri;
    const float* Wrow = W + (size_t)i * 8192 + (size_t)o * 32;
    #pragma unroll
    for (int k = 0; k < 32; ++k) {
        ws[QT_OFF + ((size_t)(sri * 32 + k) * 256 + i) * 256 + o] = Wrow[k];
    }
}

// ---------------------------------------------------------------------------
// Y[s][ri][k][p][i] = sum_o E192[p][o] * Wt[s][ri][k][i][o]
// grid (4, 3, 192): z = (s*2+ri)*32 + k
// ---------------------------------------------------------------------------
__global__ void k_gemm_Y(const float* E0, const float* E1, const float* E2, float* ws)
{
    int z = blockIdx.z;
    int k  = z & 31;
    int ri = (z >> 5) & 1;
    int s  = z >> 6;
    int L = 192 << s;
    const float* E = (s == 0) ? E0 : (s == 1) ? E1 : E2;
    const float* Ap = E + (size_t)(L - 192) * 256;
    const float* Bp = ws + QT_OFF + (size_t)((s * 2 + ri) * 32 + k) * 65536;
    float* Cp = ws + Y_OFF + (size_t)((s * 2 + ri) * 32 + k) * 49152;
    gemm_tile<true>(Ap, Bp, Cp, 192, 256, 256, blockIdx.y * 64, blockIdx.x * 64);
}

// ---------------------------------------------------------------------------
// Qd[s][ri][k][d][p] = sum_i w[s][d][i] * Y[s][ri][k][p][i]
// grid (3, 12, 192): z = (s*2+ri)*32 + k ; guard row tile against L
// ---------------------------------------------------------------------------
__global__ void k_gemm_Q(float* ws)
{
    int z = blockIdx.z;
    int k  = z & 31;
    int ri = (z >> 5) & 1;
    int s  = z >> 6;
    int L = 192 << s;
    int m0 = blockIdx.y * 64;
    if (m0 >= L) return;
    const float* Ap = ws + W_OFF + off_w_f(s);
    const float* Bp = ws + Y_OFF + (size_t)((s * 2 + ri) * 32 + k) * 49152;
    float* Cp = ws + QT_OFF + qoff_f(s) + (size_t)(ri * 32 + k) * L * 192;
    gemm_tile<true>(Ap, Bp, Cp, L, 192, 192, m0, blockIdx.x * 64);
}

// ---------------------------------------------------------------------------
// In-place twiddled prefix sum over d:
//   QG[k][n][p] = sum_{d<=n} e^{-2pi i k d / L} * Qd[k][d][p]
// grid (96): block = (s,k), 192 threads = p
// ---------------------------------------------------------------------------
__global__ void k_cumsum(float* ws)
{
    int s = blockIdx.x >> 5;
    int k = blockIdx.x & 31;
    int L = 192 << s;

    __shared__ float twc[768];
    __shared__ float tws[768];
    for (int t = threadIdx.x; t < L; t += 192) {
        float ang = -2.f * PI_F * (float)t / (float)L;
        twc[t] = cosf(ang);
        tws[t] = sinf(ang);
    }
    __syncthreads();

    int p = threadIdx.x;
    float* Qr = ws + QT_OFF + qoff_f(s) + (size_t)k * L * 192;
    float* Qi = ws + QT_OFF + qoff_f(s) + (size_t)(32 + k) * L * 192;

    float ar = 0.f, ai = 0.f;
    int ph = 0;
    for (int d = 0; d < L; ++d) {
        float qr = Qr[(size_t)d * 192 + p];
        float qi = Qi[(size_t)d * 192 + p];
        float c = twc[ph], sn = tws[ph];
        ar = fmaf(c, qr, fmaf(-sn, qi, ar));
        ai = fmaf(c, qi, fmaf( sn, qr, ai));
        Qr[(size_t)d * 192 + p] = ar;
        Qi[(size_t)d * 192 + p] = ai;
        ph += k; if (ph >= L) ph -= L;
    }
}

// ---------------------------------------------------------------------------
// Ktil[s][sidx][p] = sum_k c_k * Re( e^{+2pi i k (191 - sidx)/L} * QG[k][L-1-sidx][p] )
//   c_0 = 1/L, c_k = 2/L
// grid (1344) blocks: (s,sidx); 192 threads = p
// ---------------------------------------------------------------------------
__global__ void k_ktil(float* ws)
{
    int bid = blockIdx.x;
    int s, sidx;
    if (bid < 192)      { s = 0; sidx = bid; }
    else if (bid < 576) { s = 1; sidx = bid - 192; }
    else                { s = 2; sidx = bid - 576; }
    int L = 192 << s;
    int p = threadIdx.x;

    const float* Qbase = ws + QT_OFF + qoff_f(s);
    int d = L - 1 - sidx;
    int m1 = ((191 - sidx) % L + L) % L;

    float sum = 0.f;
    #pragma unroll
    for (int k = 0; k < 32; ++k) {
        int ph = (k * m1) % L;
        float ang = 2.f * PI_F * (float)ph / (float)L;
        float ss, cc;
        sincosf(ang, &ss, &cc);
        float ck = ((k == 0) ? 1.f : 2.f) / (float)L;
        float qr = Qbase[(size_t)k * L * 192 + (size_t)d * 192 + p];
        float qi = Qbase[(size_t)(32 + k) * L * 192 + (size_t)d * 192 + p];
        sum = fmaf(ck, fmaf(cc, qr, -ss * qi), sum);
    }
    ws[KT_OFF + ktoff_f(s) + (size_t)sidx * 192 + p] = sum;
}

// ---------------------------------------------------------------------------
// Ktot[tau][p] = sum_s (tau >= 768-L_s) mlp_w[s] * Ktil[s][tau-(768-L_s)][p]
// ---------------------------------------------------------------------------
__global__ void k_combine(float* ws, const float* mw)
{
    int idx = blockIdx.x * 256 + threadIdx.x;
    if (idx >= 147456) return;
    int tau = idx / 192;
    int p   = idx - tau * 192;
    float sum = 0.f;
    #pragma unroll
    for (int s = 0; s < 3; ++s) {
        int L = 192 << s;
        int off = 768 - L;
        if (tau >= off)
            sum = fmaf(mw[s], ws[KT_OFF + ktoff_f(s) + (size_t)(tau - off) * 192 + p], sum);
    }
    ws[KTOT_OFF + idx] = sum;
}

// ---------------------------------------------------------------------------
// out[b][p][c] = sum_tau x_enc[b][tau][c] * Ktot[tau][p] + mlp_b
// grid (336) blocks = (b,c), 192 threads = p
// ---------------------------------------------------------------------------
__global__ void k_out(const float* __restrict__ x, const float* __restrict__ ws,
                      const float* __restrict__ mb, float* __restrict__ out)
{
    int bid = blockIdx.x;
    int b = bid / 21;
    int c = bid - b * 21;
    __shared__ float xl[768];
    for (int t = threadIdx.x; t < 768; t += 192)
        xl[t] = x[((size_t)b * 768 + t) * 21 + c];
    __syncthreads();

    int p = threadIdx.x;
    const float* K = ws + KTOT_OFF;
    float acc = 0.f;
    for (int tau = 0; tau < 768; ++tau)
        acc = fmaf(xl[tau], K[(size_t)tau * 192 + p], acc);
    out[((size_t)b * 192 + p) * 21 + c] = acc + mb[0];
}

// ---------------------------------------------------------------------------
extern "C" void kernel_launch(void* const* d_in, const int* in_sizes, int n_in,
                              void* d_out, int out_size, void* d_ws, size_t ws_size,
                              hipStream_t stream)
{
    const float* x   = (const float*)d_in[0];
    const float* A0  = (const float*)d_in[1];
    const float* B0  = (const float*)d_in[2];
    const float* E0  = (const float*)d_in[3];
    const float* Wr0 = (const float*)d_in[4];
    const float* Wi0 = (const float*)d_in[5];
    const float* A1  = (const float*)d_in[6];
    const float* B1  = (const float*)d_in[7];
    const float* E1  = (const float*)d_in[8];
    const float* Wr1 = (const float*)d_in[9];
    const float* Wi1 = (const float*)d_in[10];
    const float* A2  = (const float*)d_in[11];
    const float* B2  = (const float*)d_in[12];
    const float* E2  = (const float*)d_in[13];
    const float* Wr2 = (const float*)d_in[14];
    const float* Wi2 = (const float*)d_in[15];
    const float* mw  = (const float*)d_in[16];
    const float* mb  = (const float*)d_in[17];
    float* ws  = (float*)d_ws;
    float* out = (float*)d_out;

    if (ws_size < (size_t)WS_FLOATS * sizeof(float)) {
        // workspace too small: fail loudly with a zero output (signature: err == ref absmax)
        hipMemsetAsync(d_out, 0, (size_t)out_size * sizeof(float), stream);
        return;
    }

    k_init<<<3, 256, 0, stream>>>(B0, B1, B2, ws);
    for (int n = 0; n < 10; ++n)
        k_level<<<dim3(4, 8, 3), 256, 0, stream>>>(n, A0, A1, A2, ws);
    k_transpose<<<1536, 256, 0, stream>>>(Wr0, Wi0, Wr1, Wi1, Wr2, Wi2, ws);
    k_gemm_Y<<<dim3(4, 3, 192), 256, 0, stream>>>(E0, E1, E2, ws);
    k_gemm_Q<<<dim3(3, 12, 192), 256, 0, stream>>>(ws);
    k_cumsum<<<96, 192, 0, stream>>>(ws);
    k_ktil<<<1344, 192, 0, stream>>>(ws);
    k_combine<<<576, 256, 0, stream>>>(ws, mw);
    k_out<<<336, 192, 0, stream>>>(x, ws, mb, out);
}